// Round 5
// baseline (108.587 us; speedup 1.0000x reference)
//
#include <hip/hip_runtime.h>
#include <hip/hip_bf16.h>

#define NB 8
#define NC 16
#define NH 256
#define NW 256
#define ALIVE_THRESH 0.1f
#define UPDATE_RATE 0.25f

typedef __attribute__((ext_vector_type(8))) short bf16x8;
typedef __attribute__((ext_vector_type(4))) float f32x4;
typedef unsigned short ushort_t;

#define MFMA16(a, b, c) __builtin_amdgcn_mfma_f32_16x16x32_bf16((a), (b), (c), 0, 0, 0)

static __device__ __forceinline__ unsigned short f2bf(float f) {
    __hip_bfloat16 h = __float2bfloat16(f);          // RNE
    return __builtin_bit_cast(unsigned short, h);
}
static __device__ __forceinline__ float bf2f(unsigned short b) {
    union { unsigned u; float f; } x; x.u = ((unsigned)b) << 16; return x.f;
}
static __device__ __forceinline__ unsigned pack2(float lo, float hi) {
    return (unsigned)f2bf(lo) | ((unsigned)f2bf(hi) << 16);
}
static __device__ __forceinline__ float bfbits(unsigned w, int hi) {
    return bf2f((unsigned short)(hi ? (w >> 16) : (w & 0xffffu)));
}
// channel c (compile-time in unrolled loops) from 2x uint4 = 16 bf16
static __device__ __forceinline__ float exch(const uint4& v0, const uint4& v1, int c) {
    unsigned w = (c < 8) ? ((const unsigned*)&v0)[c >> 1]
                         : ((const unsigned*)&v1)[(c - 8) >> 1];
    return bfbits(w, c & 1);
}

// swizzled byte offset into the [256 px][64 bf16] activation LDS buffer
static __device__ __forceinline__ int ybyte(int px, int g) {
    return px * 128 + ((g ^ (px & 7)) << 4);
}

// 8 consecutive f32 -> bf16x8 fragment
static __device__ __forceinline__ bf16x8 cvt8(const float* p) {
    float4 v0 = *(const float4*)p, v1 = *(const float4*)(p + 4);
    union { unsigned w[4]; bf16x8 v; } u;
    u.w[0] = pack2(v0.x, v0.y); u.w[1] = pack2(v0.z, v0.w);
    u.w[2] = pack2(v1.x, v1.y); u.w[3] = pack2(v1.z, v1.w);
    return u.v;
}

// ---------------------------------------------------------------------------
// MLP GEMM body (shared by both step kernels). yb holds y[px][64] bf16,
// each wave owns px in [wv*64, wv*64+64). Residual supplied by functor
// getres(px, lq) -> f32x4 (channels lq*4 .. lq*4+3 at pixel px).
// Output: channel-last bf16 row at outrow (= xout + ((b*NH+h)*NW)*16).
// ---------------------------------------------------------------------------
template<typename ResF>
static __device__ __forceinline__ void mlp_gemm(
    char* yb, int lane, int px0,
    const float* __restrict__ w1, const float* __restrict__ b1,
    const float* __restrict__ w2, const float* __restrict__ b2,
    const float* __restrict__ w3,
    const float* __restrict__ umr, ResF getres, ushort_t* __restrict__ outrow)
{
    const int lq = lane >> 4, ln = lane & 15;

    float umv[4];
    #pragma unroll
    for (int nt = 0; nt < 4; ++nt)
        umv[nt] = (umr[px0 + nt * 16 + ln] < UPDATE_RATE) ? 1.0f : 0.0f;

    // ---- L1: 64 <- 48(+bias row k=48), relu; h1 in place -------------------
    bf16x8 a1f[8];
    #pragma unroll
    for (int f = 0; f < 8; ++f) {
        const int m = (f >> 1) * 16 + ln;
        const int k0 = (f & 1) * 32 + lq * 8;
        if (k0 <= 40) a1f[f] = cvt8(w1 + m * 48 + k0);
        else if (k0 == 48) {
            union { unsigned w[4]; bf16x8 v; } u;
            u.w[0] = (unsigned)f2bf(b1[m]); u.w[1] = 0; u.w[2] = 0; u.w[3] = 0;
            a1f[f] = u.v;
        } else {
            union { unsigned w[4]; bf16x8 v; } u;
            u.w[0] = u.w[1] = u.w[2] = u.w[3] = 0;
            a1f[f] = u.v;
        }
    }
    #pragma unroll
    for (int nt = 0; nt < 4; ++nt) {
        const int px = px0 + nt * 16 + ln;
        bf16x8 bb0 = *(const bf16x8*)(yb + ybyte(px, lq));
        bf16x8 bb1 = *(const bf16x8*)(yb + ybyte(px, 4 + lq));
        #pragma unroll
        for (int mt = 0; mt < 4; ++mt) {
            f32x4 z = {0.f, 0.f, 0.f, 0.f};
            z = MFMA16(a1f[2 * mt],     bb0, z);
            z = MFMA16(a1f[2 * mt + 1], bb1, z);
            union { unsigned w[2]; uint2 v; } pk;
            pk.w[0] = pack2(fmaxf(z[0], 0.f), fmaxf(z[1], 0.f));
            pk.w[1] = pack2(fmaxf(z[2], 0.f), fmaxf(z[3], 0.f));
            *(uint2*)(yb + ybyte(px, 2 * mt + (lq >> 1)) + (lq & 1) * 8) = pk.v;
        }
    }

    // ---- L2: 64 <- 64, +b2, relu; h2 in place -------------------------------
    bf16x8 a2f[8];
    #pragma unroll
    for (int f = 0; f < 8; ++f)
        a2f[f] = cvt8(w2 + ((f >> 1) * 16 + ln) * 64 + (f & 1) * 32 + lq * 8);
    f32x4 b2v[4];
    #pragma unroll
    for (int mt = 0; mt < 4; ++mt)
        b2v[mt] = *(const f32x4*)(b2 + mt * 16 + lq * 4);

    #pragma unroll
    for (int nt = 0; nt < 4; ++nt) {
        const int px = px0 + nt * 16 + ln;
        bf16x8 bb0 = *(const bf16x8*)(yb + ybyte(px, lq));
        bf16x8 bb1 = *(const bf16x8*)(yb + ybyte(px, 4 + lq));
        #pragma unroll
        for (int mt = 0; mt < 4; ++mt) {
            f32x4 z = {0.f, 0.f, 0.f, 0.f};
            z = MFMA16(a2f[2 * mt],     bb0, z);
            z = MFMA16(a2f[2 * mt + 1], bb1, z);
            z = z + b2v[mt];
            union { unsigned w[2]; uint2 v; } pk;
            pk.w[0] = pack2(fmaxf(z[0], 0.f), fmaxf(z[1], 0.f));
            pk.w[1] = pack2(fmaxf(z[2], 0.f), fmaxf(z[3], 0.f));
            *(uint2*)(yb + ybyte(px, 2 * mt + (lq >> 1)) + (lq & 1) * 8) = pk.v;
        }
    }

    // ---- L3: 16 <- 64 + residual epilogue, channel-last bf16 store ----------
    bf16x8 a3f[2];
    a3f[0] = cvt8(w3 + ln * 64 + lq * 8);
    a3f[1] = cvt8(w3 + ln * 64 + 32 + lq * 8);

    #pragma unroll
    for (int nt = 0; nt < 4; ++nt) {
        const int px = px0 + nt * 16 + ln;
        bf16x8 bb0 = *(const bf16x8*)(yb + ybyte(px, lq));
        bf16x8 bb1 = *(const bf16x8*)(yb + ybyte(px, 4 + lq));
        f32x4 z = {0.f, 0.f, 0.f, 0.f};
        z = MFMA16(a3f[0], bb0, z);
        z = MFMA16(a3f[1], bb1, z);
        f32x4 res = getres(px, lq);
        union { unsigned w[2]; uint2 v; } pk;
        pk.w[0] = pack2(res[0] + z[0] * umv[nt], res[1] + z[1] * umv[nt]);
        pk.w[1] = pack2(res[2] + z[2] * umv[nt], res[3] + z[3] * umv[nt]);
        *(uint2*)(outrow + (size_t)px * 16 + lq * 4) = pk.v;
    }
}

// ---------------------------------------------------------------------------
// First step: f32 planar input -> bf16 channel-last unmasked state + pre mask.
// ---------------------------------------------------------------------------
__global__ __launch_bounds__(256) void nca_first(
    const float* __restrict__ x,
    const float* __restrict__ um,
    const float* __restrict__ w1, const float* __restrict__ b1,
    const float* __restrict__ w2, const float* __restrict__ b2,
    const float* __restrict__ w3,
    ushort_t* __restrict__ xout,
    unsigned char* __restrict__ preb_out)
{
    __shared__ char  smem[256 * 128];      // ybuf; sd overlaid at +4KB
    __shared__ float premax[NW];

    char*     yb = smem;
    unsigned* sd = (unsigned*)(smem + 4096);

    const int t = threadIdx.x, bx = blockIdx.x;
    const int h = ((bx & 7) << 5) | (bx >> 3);      // XCD-chunked row swizzle
    const int b = blockIdx.y;
    const int hm = (h - 1) & 255, hp = (h + 1) & 255;
    const size_t cs = (size_t)NH * NW;
    const size_t base = (size_t)b * NC * cs;

    float mreg[NC], dreg[NC];
    #pragma unroll
    for (int c = 0; c < NC; ++c) {
        const float* xc = x + base + (size_t)c * cs;
        float top = xc[(size_t)hm * NW + t];
        float mid = xc[(size_t)h  * NW + t];
        float bot = xc[(size_t)hp * NW + t];
        sd[c * NW + t] = pack2(top + 2.0f * mid + bot, bot - top);
        mreg[c] = mid; dreg[c] = bot - top;
        if (c == 3) premax[t] = fmaxf(fmaxf(top, mid), bot);
    }
    __syncthreads();                                 // B1: sd + premax ready

    const int tm = (t - 1) & 255, tp = (t + 1) & 255;
    {
        float mx = fmaxf(fmaxf(premax[tm], premax[t]), premax[tp]);
        preb_out[((size_t)b * NH + h) * NW + t] = (mx > ALIVE_THRESH) ? 1 : 0;
    }

    unsigned yp[24];
    {
        unsigned short ys[48];
        #pragma unroll
        for (int c = 0; c < NC; ++c) {
            unsigned L = sd[c * NW + tm], R = sd[c * NW + tp];
            float sl = bfbits(L, 0), dl = bfbits(L, 1);
            float sr = bfbits(R, 0), dr = bfbits(R, 1);
            ys[3 * c + 0] = f2bf(mreg[c]);
            ys[3 * c + 1] = f2bf(sr - sl);
            ys[3 * c + 2] = f2bf(dl + 2.0f * dreg[c] + dr);
        }
        #pragma unroll
        for (int i = 0; i < 24; ++i)
            yp[i] = (unsigned)ys[2 * i] | ((unsigned)ys[2 * i + 1] << 16);
    }
    __syncthreads();                                 // B2: sd dead, ybuf safe

    #pragma unroll
    for (int g = 0; g < 6; ++g) {
        union { unsigned w[4]; int4 v; } pk;
        pk.w[0] = yp[4 * g]; pk.w[1] = yp[4 * g + 1];
        pk.w[2] = yp[4 * g + 2]; pk.w[3] = yp[4 * g + 3];
        *(int4*)(yb + ybyte(t, g)) = pk.v;
    }
    { int4 br; br.x = 0x3F80; br.y = 0; br.z = 0; br.w = 0;
      *(int4*)(yb + ybyte(t, 6)) = br; }             // k=48 -> 1.0 (bias)
    { int4 zz; zz.x = zz.y = zz.z = zz.w = 0;
      *(int4*)(yb + ybyte(t, 7)) = zz; }

    const int lane = t & 63, wv = t >> 6;
    const float* umr = um + ((size_t)b * NH + h) * NW;
    ushort_t* outrow = xout + ((size_t)(b * NH + h) * NW) * 16;

    auto getres = [&](int px, int lq) -> f32x4 {
        f32x4 r;
        #pragma unroll
        for (int i = 0; i < 4; ++i)
            r[i] = x[base + (size_t)(lq * 4 + i) * cs + (size_t)h * NW + px];
        return r;
    };
    mlp_gemm(yb, lane, wv * 64, w1, b1, w2, b2, w3, umr, getres, outrow);
}

// ---------------------------------------------------------------------------
// Later steps: bf16 channel-last unmasked state + pre mask of prev step in;
// reconstruct pre*post on the fly (5x5 alpha window, registers only),
// emit this step's pre + new unmasked state.
// ---------------------------------------------------------------------------
__global__ __launch_bounds__(256) void nca_step(
    const ushort_t* __restrict__ xin,
    const unsigned char* __restrict__ preb_in,
    const float* __restrict__ um,
    const float* __restrict__ w1, const float* __restrict__ b1,
    const float* __restrict__ w2, const float* __restrict__ b2,
    const float* __restrict__ w3,
    ushort_t* __restrict__ xout,
    unsigned char* __restrict__ preb_out)
{
    __shared__ char  smem[256 * 128];      // ybuf; sd overlaid at +4KB
    __shared__ float mmid[NW];

    char*     yb = smem;
    unsigned* sd = (unsigned*)(smem + 4096);

    const int t = threadIdx.x, bx = blockIdx.x;
    const int h = ((bx & 7) << 5) | (bx >> 3);
    const int b = blockIdx.y;
    const size_t prow = (size_t)b * NH;

    // ---- state column (rows h-1..h+1, px t) + 5x5 alpha window -------------
    float a[5][5];
    uint4 sv[3][2];
    #pragma unroll
    for (int r = 0; r < 3; ++r) {
        const size_t e = ((prow + ((h - 1 + r) & 255)) * NW + t) * 16;
        sv[r][0] = *(const uint4*)(xin + e);
        sv[r][1] = *(const uint4*)(xin + e + 8);
        a[1 + r][2] = bfbits(sv[r][0].y, 1);          // channel 3
    }
    #pragma unroll
    for (int j = 0; j < 5; ++j) {
        const int hh = (h - 2 + j) & 255;
        const size_t rb = (prow + hh) * NW * 16 + 3;
        #pragma unroll
        for (int d = 0; d < 5; ++d) {
            if (j >= 1 && j <= 3 && d == 2) continue; // already extracted
            const int uu = (t - 2 + d) & 255;
            a[j][d] = bf2f(xin[rb + (size_t)uu * 16]);
        }
    }

    // ---- post(prev) & combined masks for rows h-1..h+1 at px t-1..t+1 ------
    float m3x3[3][3];
    #pragma unroll
    for (int r = 0; r < 3; ++r) {
        float cm[5];
        #pragma unroll
        for (int d = 0; d < 5; ++d)
            cm[d] = fmaxf(fmaxf(a[r][d], a[r + 1][d]), a[r + 2][d]);
        #pragma unroll
        for (int dd = 0; dd < 3; ++dd) {
            float post = fmaxf(fmaxf(cm[dd], cm[dd + 1]), cm[dd + 2]);
            const int hh = (h - 1 + r) & 255, uu = (t - 1 + dd) & 255;
            unsigned char p = preb_in[(prow + hh) * NW + uu];
            m3x3[r][dd] = (post > ALIVE_THRESH && p) ? 1.0f : 0.0f;
        }
    }

    // ---- pre mask of THIS step (alive of masked state) ----------------------
    {
        float pm = 0.0f;
        #pragma unroll
        for (int r = 0; r < 3; ++r)
            #pragma unroll
            for (int dd = 0; dd < 3; ++dd)
                pm = fmaxf(pm, a[1 + r][1 + dd] * m3x3[r][dd]);
        preb_out[(prow + h) * NW + t] = (pm > ALIVE_THRESH) ? 1 : 0;
    }

    const float m0 = m3x3[0][1], m1 = m3x3[1][1], m2 = m3x3[2][1];
    mmid[t] = m1;                                    // intra-wave consumers only

    // ---- vertical smooth/diff on masked state -> sd LDS ---------------------
    float mreg[NC], dreg[NC];
    #pragma unroll
    for (int c = 0; c < NC; ++c) {
        float top = exch(sv[0][0], sv[0][1], c) * m0;
        float mid = exch(sv[1][0], sv[1][1], c) * m1;
        float bot = exch(sv[2][0], sv[2][1], c) * m2;
        sd[c * NW + t] = pack2(top + 2.0f * mid + bot, bot - top);
        mreg[c] = mid; dreg[c] = bot - top;
    }
    __syncthreads();                                 // B1: sd ready

    const int tm = (t - 1) & 255, tp = (t + 1) & 255;
    unsigned yp[24];
    {
        unsigned short ys[48];
        #pragma unroll
        for (int c = 0; c < NC; ++c) {
            unsigned L = sd[c * NW + tm], R = sd[c * NW + tp];
            float sl = bfbits(L, 0), dl = bfbits(L, 1);
            float sr = bfbits(R, 0), dr = bfbits(R, 1);
            ys[3 * c + 0] = f2bf(mreg[c]);
            ys[3 * c + 1] = f2bf(sr - sl);
            ys[3 * c + 2] = f2bf(dl + 2.0f * dreg[c] + dr);
        }
        #pragma unroll
        for (int i = 0; i < 24; ++i)
            yp[i] = (unsigned)ys[2 * i] | ((unsigned)ys[2 * i + 1] << 16);
    }
    __syncthreads();                                 // B2: sd dead, ybuf safe

    #pragma unroll
    for (int g = 0; g < 6; ++g) {
        union { unsigned w[4]; int4 v; } pk;
        pk.w[0] = yp[4 * g]; pk.w[1] = yp[4 * g + 1];
        pk.w[2] = yp[4 * g + 2]; pk.w[3] = yp[4 * g + 3];
        *(int4*)(yb + ybyte(t, g)) = pk.v;
    }
    { int4 br; br.x = 0x3F80; br.y = 0; br.z = 0; br.w = 0;
      *(int4*)(yb + ybyte(t, 6)) = br; }
    { int4 zz; zz.x = zz.y = zz.z = zz.w = 0;
      *(int4*)(yb + ybyte(t, 7)) = zz; }

    const int lane = t & 63, wv = t >> 6;
    const float* umr = um + (prow + h) * NW;
    const ushort_t* inrow = xin + ((prow + h) * NW) * 16;
    ushort_t* outrow = xout + ((prow + h) * NW) * 16;

    auto getres = [&](int px, int lq) -> f32x4 {
        uint2 v = *(const uint2*)(inrow + (size_t)px * 16 + lq * 4);
        const float mm = mmid[px];                   // same wave wrote it
        f32x4 r;
        r[0] = bfbits(v.x, 0) * mm; r[1] = bfbits(v.x, 1) * mm;
        r[2] = bfbits(v.y, 0) * mm; r[3] = bfbits(v.y, 1) * mm;
        return r;
    };
    mlp_gemm(yb, lane, wv * 64, w1, b1, w2, b2, w3, umr, getres, outrow);
}

// ---------------------------------------------------------------------------
// Final: post-alive on channel-last bf16 state, apply pre*post, f32 planar out.
// Zero LDS, zero barriers.
// ---------------------------------------------------------------------------
__global__ __launch_bounds__(256) void nca_final(
    const ushort_t* __restrict__ xin,
    const unsigned char* __restrict__ preb,
    float* __restrict__ xout)
{
    const int t = threadIdx.x, bx = blockIdx.x;
    const int h = ((bx & 7) << 5) | (bx >> 3);
    const int b = blockIdx.y;
    const size_t prow = (size_t)b * NH;

    const size_t e = ((prow + h) * NW + t) * 16;
    uint4 s0 = *(const uint4*)(xin + e);
    uint4 s1 = *(const uint4*)(xin + e + 8);

    float mx = bfbits(s0.y, 1);                      // own alpha
    #pragma unroll
    for (int r = 0; r < 3; ++r)
        #pragma unroll
        for (int d = 0; d < 3; ++d) {
            if (r == 1 && d == 1) continue;
            const int hh = (h - 1 + r) & 255, uu = (t - 1 + d) & 255;
            mx = fmaxf(mx, bf2f(xin[((prow + hh) * NW + uu) * 16 + 3]));
        }
    const float m = (mx > ALIVE_THRESH && preb[(prow + h) * NW + t]) ? 1.0f : 0.0f;

    const size_t cs = (size_t)NH * NW;
    const size_t obase = (size_t)b * NC * cs + (size_t)h * NW + t;
    #pragma unroll
    for (int c = 0; c < NC; ++c)
        xout[obase + (size_t)c * cs] = exch(s0, s1, c) * m;
}

// ---------------------------------------------------------------------------
extern "C" void kernel_launch(void* const* d_in, const int* in_sizes, int n_in,
                              void* d_out, int out_size, void* d_ws, size_t ws_size,
                              hipStream_t stream) {
    const float* x  = (const float*)d_in[0];
    const float* w1 = (const float*)d_in[1];
    const float* b1 = (const float*)d_in[2];
    const float* w2 = (const float*)d_in[3];
    const float* b2 = (const float*)d_in[4];
    const float* w3 = (const float*)d_in[5];
    const float* um = (const float*)d_in[6];
    const int steps = in_sizes[6] / (NB * NH * NW);

    const size_t npix  = (size_t)NB * NH * NW;
    const size_t nelem = (size_t)NB * NC * NH * NW;

    ushort_t* bfA        = (ushort_t*)d_ws;                 // 16 MB
    ushort_t* bfB        = bfA + nelem;                     // 16 MB
    unsigned char* prebA = (unsigned char*)(bfB + nelem);   // 512 KB
    unsigned char* prebB = prebA + npix;                    // 512 KB
    float* xout          = (float*)d_out;

    dim3 grd(NH, NB);

    const ushort_t* cur = bfA;
    unsigned char* preb_last = prebA;

    for (int i = 0; i < steps; ++i) {
        const float* um_i = um + (size_t)i * npix;
        ushort_t* bfo      = (i % 2 == 0) ? bfA : bfB;
        unsigned char* po  = (i % 2 == 0) ? prebA : prebB;
        unsigned char* pin = (i % 2 == 0) ? prebB : prebA;

        if (i == 0)
            nca_first<<<grd, 256, 0, stream>>>(x, um_i, w1, b1, w2, b2, w3,
                                               bfo, po);
        else
            nca_step<<<grd, 256, 0, stream>>>(cur, pin, um_i, w1, b1, w2, b2, w3,
                                              bfo, po);
        cur = bfo;
        preb_last = po;
    }

    nca_final<<<grd, 256, 0, stream>>>(cur, preb_last, xout);
}

// Round 6
// 98.304 us; speedup vs baseline: 1.1046x; 1.1046x over previous
//
#include <hip/hip_runtime.h>
#include <hip/hip_bf16.h>

#define NB 8
#define NC 16
#define NH 256
#define NW 256
#define ALIVE_THRESH 0.1f
#define UPDATE_RATE 0.25f

typedef __attribute__((ext_vector_type(8))) short bf16x8;
typedef __attribute__((ext_vector_type(4))) float f32x4;
typedef unsigned short ushort_t;

#define MFMA16(a, b, c) __builtin_amdgcn_mfma_f32_16x16x32_bf16((a), (b), (c), 0, 0, 0)

static __device__ __forceinline__ unsigned short f2bf(float f) {
    __hip_bfloat16 h = __float2bfloat16(f);          // RNE
    return __builtin_bit_cast(unsigned short, h);
}
static __device__ __forceinline__ float bf2f(unsigned short b) {
    union { unsigned u; float f; } x; x.u = ((unsigned)b) << 16; return x.f;
}
static __device__ __forceinline__ unsigned pack2(float lo, float hi) {
    return (unsigned)f2bf(lo) | ((unsigned)f2bf(hi) << 16);
}
static __device__ __forceinline__ float bfbits(unsigned w, int hi) {
    return bf2f((unsigned short)(hi ? (w >> 16) : (w & 0xffffu)));
}

// swizzled byte offset into the [256 px][64 bf16] activation LDS buffer
static __device__ __forceinline__ int ybyte(int px, int g) {
    return px * 128 + ((g ^ (px & 7)) << 4);
}

// 8 consecutive f32 -> bf16x8 fragment (global loads, no address-of-register)
static __device__ __forceinline__ bf16x8 cvt8(const float* p) {
    float4 v0 = *(const float4*)p, v1 = *(const float4*)(p + 4);
    union { unsigned w[4]; bf16x8 v; } u;
    u.w[0] = pack2(v0.x, v0.y); u.w[1] = pack2(v0.z, v0.w);
    u.w[2] = pack2(v1.x, v1.y); u.w[3] = pack2(v1.z, v1.w);
    return u.v;
}

// ---------------------------------------------------------------------------
// MLP GEMM body. yb holds y[px][64] bf16; wave wv owns px in [wv*64, wv*64+64).
// Weight fragments built from raw f32 weights (L2-hot). Residual via functor
// getres(px, lq, nt) -> f32x4 (channels lq*4..lq*4+3 at pixel px).
// Output: planar bf16 store via putout(px, lq, r, val).
// ---------------------------------------------------------------------------
template<typename ResF, typename OutF>
static __device__ __forceinline__ void mlp_gemm(
    char* yb, int lane, int px0,
    const float* __restrict__ w1, const float* __restrict__ b1,
    const float* __restrict__ w2, const float* __restrict__ b2,
    const float* __restrict__ w3,
    const float* __restrict__ umr, ResF getres, OutF putout)
{
    const int lq = lane >> 4, ln = lane & 15;

    float umv[4];
    #pragma unroll
    for (int nt = 0; nt < 4; ++nt)
        umv[nt] = (umr[px0 + nt * 16 + ln] < UPDATE_RATE) ? 1.0f : 0.0f;

    // ---- L1: 64 <- 48(+bias row k=48), relu; h1 in place -------------------
    bf16x8 a1f[8];
    #pragma unroll
    for (int f = 0; f < 8; ++f) {
        const int m = (f >> 1) * 16 + ln;
        const int k0 = (f & 1) * 32 + lq * 8;
        if (k0 <= 40) a1f[f] = cvt8(w1 + m * 48 + k0);
        else if (k0 == 48) {
            union { unsigned w[4]; bf16x8 v; } u;
            u.w[0] = (unsigned)f2bf(b1[m]); u.w[1] = 0; u.w[2] = 0; u.w[3] = 0;
            a1f[f] = u.v;
        } else {
            union { unsigned w[4]; bf16x8 v; } u;
            u.w[0] = u.w[1] = u.w[2] = u.w[3] = 0;
            a1f[f] = u.v;
        }
    }
    #pragma unroll
    for (int nt = 0; nt < 4; ++nt) {
        const int px = px0 + nt * 16 + ln;
        bf16x8 bb0 = *(const bf16x8*)(yb + ybyte(px, lq));
        bf16x8 bb1 = *(const bf16x8*)(yb + ybyte(px, 4 + lq));
        #pragma unroll
        for (int mt = 0; mt < 4; ++mt) {
            f32x4 z = {0.f, 0.f, 0.f, 0.f};
            z = MFMA16(a1f[2 * mt],     bb0, z);
            z = MFMA16(a1f[2 * mt + 1], bb1, z);
            union { unsigned w[2]; uint2 v; } pk;
            pk.w[0] = pack2(fmaxf(z[0], 0.f), fmaxf(z[1], 0.f));
            pk.w[1] = pack2(fmaxf(z[2], 0.f), fmaxf(z[3], 0.f));
            *(uint2*)(yb + ybyte(px, 2 * mt + (lq >> 1)) + (lq & 1) * 8) = pk.v;
        }
    }

    // ---- L2: 64 <- 64, +b2, relu; h2 in place -------------------------------
    bf16x8 a2f[8];
    #pragma unroll
    for (int f = 0; f < 8; ++f)
        a2f[f] = cvt8(w2 + ((f >> 1) * 16 + ln) * 64 + (f & 1) * 32 + lq * 8);
    f32x4 b2v[4];
    #pragma unroll
    for (int mt = 0; mt < 4; ++mt)
        b2v[mt] = *(const f32x4*)(b2 + mt * 16 + lq * 4);

    #pragma unroll
    for (int nt = 0; nt < 4; ++nt) {
        const int px = px0 + nt * 16 + ln;
        bf16x8 bb0 = *(const bf16x8*)(yb + ybyte(px, lq));
        bf16x8 bb1 = *(const bf16x8*)(yb + ybyte(px, 4 + lq));
        #pragma unroll
        for (int mt = 0; mt < 4; ++mt) {
            f32x4 z = {0.f, 0.f, 0.f, 0.f};
            z = MFMA16(a2f[2 * mt],     bb0, z);
            z = MFMA16(a2f[2 * mt + 1], bb1, z);
            z = z + b2v[mt];
            union { unsigned w[2]; uint2 v; } pk;
            pk.w[0] = pack2(fmaxf(z[0], 0.f), fmaxf(z[1], 0.f));
            pk.w[1] = pack2(fmaxf(z[2], 0.f), fmaxf(z[3], 0.f));
            *(uint2*)(yb + ybyte(px, 2 * mt + (lq >> 1)) + (lq & 1) * 8) = pk.v;
        }
    }

    // ---- L3: 16 <- 64 + residual epilogue -----------------------------------
    bf16x8 a3f0 = cvt8(w3 + (lane & 15) * 64 + lq * 8);
    bf16x8 a3f1 = cvt8(w3 + (lane & 15) * 64 + 32 + lq * 8);

    #pragma unroll
    for (int nt = 0; nt < 4; ++nt) {
        const int px = px0 + nt * 16 + ln;
        bf16x8 bb0 = *(const bf16x8*)(yb + ybyte(px, lq));
        bf16x8 bb1 = *(const bf16x8*)(yb + ybyte(px, 4 + lq));
        f32x4 z = {0.f, 0.f, 0.f, 0.f};
        z = MFMA16(a3f0, bb0, z);
        z = MFMA16(a3f1, bb1, z);
        f32x4 res = getres(px, lq, nt);
        #pragma unroll
        for (int r = 0; r < 4; ++r)
            putout(px, lq, r, res[r] + z[r] * umv[nt]);
    }
}

// ---------------------------------------------------------------------------
// First step: f32 planar input -> bf16 planar unmasked state + pre mask.
// LDS exactly 32 KB (sd overlays ybuf; live ranges disjoint across B2).
// ---------------------------------------------------------------------------
__global__ __launch_bounds__(256) void nca_first(
    const float* __restrict__ x,
    const float* __restrict__ um,
    const float* __restrict__ w1, const float* __restrict__ b1,
    const float* __restrict__ w2, const float* __restrict__ b2,
    const float* __restrict__ w3,
    ushort_t* __restrict__ xout,
    unsigned char* __restrict__ preb_out)
{
    __shared__ char smem[256 * 128];          // 32 KB
    char*     yb = smem;
    unsigned* sd = (unsigned*)smem;           // [NC][NW], dead after B2

    const int t = threadIdx.x, bx = blockIdx.x;
    const int h = ((bx & 7) << 5) | (bx >> 3);       // XCD-chunked row swizzle
    const int b = blockIdx.y;
    const int hm = (h - 1) & 255, hp = (h + 1) & 255;
    const size_t cs = (size_t)NH * NW;
    const size_t base = (size_t)b * NC * cs;

    // ---- pre-alive: own 3x3 f32 alpha window (coalesced, cache-hot) --------
    {
        const float* a3p = x + base + 3 * cs;
        float mx = -1e30f;
        #pragma unroll
        for (int r = 0; r < 3; ++r) {
            const float* rp = a3p + (size_t)((h - 1 + r) & 255) * NW;
            #pragma unroll
            for (int d = 0; d < 3; ++d)
                mx = fmaxf(mx, rp[(t - 1 + d) & 255]);
        }
        preb_out[((size_t)b * NH + h) * NW + t] = (mx > ALIVE_THRESH) ? 1 : 0;
    }

    // ---- vertical smooth/diff -> sd -----------------------------------------
    float mreg[NC], dreg[NC];
    #pragma unroll
    for (int c = 0; c < NC; ++c) {
        const float* xc = x + base + (size_t)c * cs;
        float top = xc[(size_t)hm * NW + t];
        float mid = xc[(size_t)h  * NW + t];
        float bot = xc[(size_t)hp * NW + t];
        sd[c * NW + t] = pack2(top + 2.0f * mid + bot, bot - top);
        mreg[c] = mid; dreg[c] = bot - top;
    }
    __syncthreads();                                  // B1: sd ready

    const int tm = (t - 1) & 255, tp = (t + 1) & 255;
    unsigned yp[24];
    {
        unsigned short ys[48];
        #pragma unroll
        for (int c = 0; c < NC; ++c) {
            unsigned L = sd[c * NW + tm], R = sd[c * NW + tp];
            float sl = bfbits(L, 0), dl = bfbits(L, 1);
            float sr = bfbits(R, 0), dr = bfbits(R, 1);
            ys[3 * c + 0] = f2bf(mreg[c]);
            ys[3 * c + 1] = f2bf(sr - sl);
            ys[3 * c + 2] = f2bf(dl + 2.0f * dreg[c] + dr);
        }
        #pragma unroll
        for (int i = 0; i < 24; ++i)
            yp[i] = (unsigned)ys[2 * i] | ((unsigned)ys[2 * i + 1] << 16);
    }
    __syncthreads();                                  // B2: sd dead, ybuf safe

    #pragma unroll
    for (int g = 0; g < 6; ++g) {
        union { unsigned w[4]; int4 v; } pk;
        pk.w[0] = yp[4 * g]; pk.w[1] = yp[4 * g + 1];
        pk.w[2] = yp[4 * g + 2]; pk.w[3] = yp[4 * g + 3];
        *(int4*)(yb + ybyte(t, g)) = pk.v;
    }
    { int4 br; br.x = 0x3F80; br.y = 0; br.z = 0; br.w = 0;
      *(int4*)(yb + ybyte(t, 6)) = br; }              // k=48 -> 1.0 (bias)
    { int4 zz; zz.x = zz.y = zz.z = zz.w = 0;
      *(int4*)(yb + ybyte(t, 7)) = zz; }

    const int lane = t & 63, wv = t >> 6;
    const float* umr = um + ((size_t)b * NH + h) * NW;

    auto getres = [&](int px, int lq, int) -> f32x4 {
        f32x4 r;
        #pragma unroll
        for (int i = 0; i < 4; ++i)
            r[i] = x[base + (size_t)(lq * 4 + i) * cs + (size_t)h * NW + px];
        return r;
    };
    auto putout = [&](int px, int lq, int r, float v) {
        xout[base + (size_t)(lq * 4 + r) * cs + (size_t)h * NW + px] = f2bf(v);
    };
    mlp_gemm(yb, lane, wv * 64, w1, b1, w2, b2, w3, umr, getres, putout);
}

// ---------------------------------------------------------------------------
// Later steps: bf16 planar unmasked state + prev pre mask in; reconstruct
// pre*post masks in REGISTERS (5x5 planar alpha window, all coalesced).
// ---------------------------------------------------------------------------
__global__ __launch_bounds__(256) void nca_step(
    const ushort_t* __restrict__ xin,
    const unsigned char* __restrict__ preb_in,
    const float* __restrict__ um,
    const float* __restrict__ w1, const float* __restrict__ b1,
    const float* __restrict__ w2, const float* __restrict__ b2,
    const float* __restrict__ w3,
    ushort_t* __restrict__ xout,
    unsigned char* __restrict__ preb_out)
{
    __shared__ char smem[256 * 128];          // 32 KB
    char*     yb = smem;
    unsigned* sd = (unsigned*)smem;

    const int t = threadIdx.x, bx = blockIdx.x;
    const int h = ((bx & 7) << 5) | (bx >> 3);
    const int b = blockIdx.y;
    const int hm = (h - 1) & 255, hp = (h + 1) & 255;
    const size_t cs = (size_t)NH * NW;
    const size_t base = (size_t)b * NC * cs;
    const size_t prow = (size_t)b * NH;

    // ---- 5x5 alpha window (planar, coalesced) -------------------------------
    float a[5][5];
    {
        const ushort_t* a3p = xin + base + 3 * cs;
        #pragma unroll
        for (int j = 0; j < 5; ++j) {
            const ushort_t* rp = a3p + (size_t)((h - 2 + j) & 255) * NW;
            #pragma unroll
            for (int d = 0; d < 5; ++d)
                a[j][d] = bf2f(rp[(t - 2 + d) & 255]);
        }
    }

    // ---- post(prev) & combined masks for rows h-1..h+1, cols t-1..t+1 ------
    float m3x3[3][3];
    #pragma unroll
    for (int r = 0; r < 3; ++r) {
        float cm[5];
        #pragma unroll
        for (int d = 0; d < 5; ++d)
            cm[d] = fmaxf(fmaxf(a[r][d], a[r + 1][d]), a[r + 2][d]);
        #pragma unroll
        for (int dd = 0; dd < 3; ++dd) {
            float post = fmaxf(fmaxf(cm[dd], cm[dd + 1]), cm[dd + 2]);
            const int hh = (h - 1 + r) & 255, uu = (t - 1 + dd) & 255;
            unsigned char p = preb_in[(prow + hh) * NW + uu];
            m3x3[r][dd] = (post > ALIVE_THRESH && p) ? 1.0f : 0.0f;
        }
    }

    // ---- pre mask of THIS step ----------------------------------------------
    {
        float pm = 0.0f;
        #pragma unroll
        for (int r = 0; r < 3; ++r)
            #pragma unroll
            for (int dd = 0; dd < 3; ++dd)
                pm = fmaxf(pm, a[1 + r][1 + dd] * m3x3[r][dd]);
        preb_out[(prow + h) * NW + t] = (pm > ALIVE_THRESH) ? 1 : 0;
    }

    const float m0 = m3x3[0][1], m1 = m3x3[1][1], m2 = m3x3[2][1];

    // ---- vertical smooth/diff on masked state -> sd (planar loads) ----------
    float mreg[NC], dreg[NC];
    #pragma unroll
    for (int c = 0; c < NC; ++c) {
        float top, mid, bot;
        if (c == 3) { top = a[1][2] * m0; mid = a[2][2] * m1; bot = a[3][2] * m2; }
        else {
            const ushort_t* xc = xin + base + (size_t)c * cs;
            top = bf2f(xc[(size_t)hm * NW + t]) * m0;
            mid = bf2f(xc[(size_t)h  * NW + t]) * m1;
            bot = bf2f(xc[(size_t)hp * NW + t]) * m2;
        }
        sd[c * NW + t] = pack2(top + 2.0f * mid + bot, bot - top);
        mreg[c] = mid; dreg[c] = bot - top;
    }
    __syncthreads();                                  // B1: sd ready

    const int tm = (t - 1) & 255, tp = (t + 1) & 255;
    unsigned yp[24];
    {
        unsigned short ys[48];
        #pragma unroll
        for (int c = 0; c < NC; ++c) {
            unsigned L = sd[c * NW + tm], R = sd[c * NW + tp];
            float sl = bfbits(L, 0), dl = bfbits(L, 1);
            float sr = bfbits(R, 0), dr = bfbits(R, 1);
            ys[3 * c + 0] = f2bf(mreg[c]);
            ys[3 * c + 1] = f2bf(sr - sl);
            ys[3 * c + 2] = f2bf(dl + 2.0f * dreg[c] + dr);
        }
        #pragma unroll
        for (int i = 0; i < 24; ++i)
            yp[i] = (unsigned)ys[2 * i] | ((unsigned)ys[2 * i + 1] << 16);
    }
    __syncthreads();                                  // B2: sd dead, ybuf safe

    #pragma unroll
    for (int g = 0; g < 6; ++g) {
        union { unsigned w[4]; int4 v; } pk;
        pk.w[0] = yp[4 * g]; pk.w[1] = yp[4 * g + 1];
        pk.w[2] = yp[4 * g + 2]; pk.w[3] = yp[4 * g + 3];
        *(int4*)(yb + ybyte(t, g)) = pk.v;
    }
    { int4 br; br.x = 0x3F80; br.y = 0; br.z = 0; br.w = 0;
      *(int4*)(yb + ybyte(t, 6)) = br; }
    { int4 zz; zz.x = zz.y = zz.z = zz.w = 0;
      *(int4*)(yb + ybyte(t, 7)) = zz; }

    const int lane = t & 63, wv = t >> 6;
    const float* umr = um + (prow + h) * NW;

    // residual mask for px via wave shuffle (wave wv owns px = wv*64 + lane)
    auto getres = [&](int px, int lq, int) -> f32x4 {
        const float mm = __shfl(m1, px & 63);
        f32x4 r;
        #pragma unroll
        for (int i = 0; i < 4; ++i)
            r[i] = bf2f(xin[base + (size_t)(lq * 4 + i) * cs + (size_t)h * NW + px]) * mm;
        return r;
    };
    auto putout = [&](int px, int lq, int r, float v) {
        xout[base + (size_t)(lq * 4 + r) * cs + (size_t)h * NW + px] = f2bf(v);
    };
    mlp_gemm(yb, lane, wv * 64, w1, b1, w2, b2, w3, umr, getres, putout);
}

// ---------------------------------------------------------------------------
// Final: post-alive on bf16 planar state, apply pre*post, f32 planar out.
// Zero LDS, zero barriers.
// ---------------------------------------------------------------------------
__global__ __launch_bounds__(256) void nca_final(
    const ushort_t* __restrict__ xin,
    const unsigned char* __restrict__ preb,
    float* __restrict__ xout)
{
    const int t = threadIdx.x, bx = blockIdx.x;
    const int h = ((bx & 7) << 5) | (bx >> 3);
    const int b = blockIdx.y;
    const size_t cs = (size_t)NH * NW;
    const size_t base = (size_t)b * NC * cs;

    const ushort_t* a3p = xin + base + 3 * cs;
    float mx = -1e30f;
    #pragma unroll
    for (int r = 0; r < 3; ++r) {
        const ushort_t* rp = a3p + (size_t)((h - 1 + r) & 255) * NW;
        #pragma unroll
        for (int d = 0; d < 3; ++d)
            mx = fmaxf(mx, bf2f(rp[(t - 1 + d) & 255]));
    }
    const float m = (mx > ALIVE_THRESH && preb[((size_t)b * NH + h) * NW + t])
                        ? 1.0f : 0.0f;

    const size_t off = (size_t)h * NW + t;
    #pragma unroll
    for (int c = 0; c < NC; ++c)
        xout[base + (size_t)c * cs + off] = bf2f(xin[base + (size_t)c * cs + off]) * m;
}

// ---------------------------------------------------------------------------
extern "C" void kernel_launch(void* const* d_in, const int* in_sizes, int n_in,
                              void* d_out, int out_size, void* d_ws, size_t ws_size,
                              hipStream_t stream) {
    const float* x  = (const float*)d_in[0];
    const float* w1 = (const float*)d_in[1];
    const float* b1 = (const float*)d_in[2];
    const float* w2 = (const float*)d_in[3];
    const float* b2 = (const float*)d_in[4];
    const float* w3 = (const float*)d_in[5];
    const float* um = (const float*)d_in[6];
    const int steps = in_sizes[6] / (NB * NH * NW);

    const size_t npix  = (size_t)NB * NH * NW;
    const size_t nelem = (size_t)NB * NC * NH * NW;

    ushort_t* bfA        = (ushort_t*)d_ws;                 // 16 MB
    ushort_t* bfB        = bfA + nelem;                     // 16 MB
    unsigned char* prebA = (unsigned char*)(bfB + nelem);   // 512 KB
    unsigned char* prebB = prebA + npix;                    // 512 KB
    float* xout          = (float*)d_out;

    dim3 grd(NH, NB);

    const ushort_t* cur = bfA;
    unsigned char* preb_last = prebA;

    for (int i = 0; i < steps; ++i) {
        const float* um_i = um + (size_t)i * npix;
        ushort_t* bfo      = (i % 2 == 0) ? bfA : bfB;
        unsigned char* po  = (i % 2 == 0) ? prebA : prebB;
        unsigned char* pin = (i % 2 == 0) ? prebB : prebA;

        if (i == 0)
            nca_first<<<grd, 256, 0, stream>>>(x, um_i, w1, b1, w2, b2, w3,
                                               bfo, po);
        else
            nca_step<<<grd, 256, 0, stream>>>(cur, pin, um_i, w1, b1, w2, b2, w3,
                                              bfo, po);
        cur = bfo;
        preb_last = po;
    }

    nca_final<<<grd, 256, 0, stream>>>(cur, preb_last, xout);
}

// Round 7
// 64.487 us; speedup vs baseline: 1.6839x; 1.5244x over previous
//
#include <hip/hip_runtime.h>
#include <hip/hip_bf16.h>

#define NB 8
#define NC 16
#define NH 256
#define NW 256
#define ALIVE_THRESH 0.1f
#define UPDATE_RATE 0.25f

typedef __attribute__((ext_vector_type(8))) short bf16x8;
typedef __attribute__((ext_vector_type(4))) float f32x4;
typedef unsigned short ushort_t;

#define MFMA16(a, b, c) __builtin_amdgcn_mfma_f32_16x16x32_bf16((a), (b), (c), 0, 0, 0)

static __device__ __forceinline__ unsigned short f2bf(float f) {
    __hip_bfloat16 h = __float2bfloat16(f);          // RNE
    return __builtin_bit_cast(unsigned short, h);
}
static __device__ __forceinline__ float bf2f(unsigned short b) {
    union { unsigned u; float f; } x; x.u = ((unsigned)b) << 16; return x.f;
}
static __device__ __forceinline__ unsigned pack2(float lo, float hi) {
    return (unsigned)f2bf(lo) | ((unsigned)f2bf(hi) << 16);
}
static __device__ __forceinline__ float bfbits(unsigned w, int hi) {
    return bf2f((unsigned short)(hi ? (w >> 16) : (w & 0xffffu)));
}

// swizzled byte offset into the [256 px][64 bf16] activation LDS buffer
static __device__ __forceinline__ int ybyte(int px, int g) {
    return px * 128 + ((g ^ (px & 7)) << 4);
}

// ---------------------------------------------------------------------------
// Pre-kernel: pack W1(+b1 as k=48 row), W2, W3 into MFMA A-fragment order.
// frag f, lane l -> 8 bf16 (int4). Coalesced consumption: wf[f*64 + lane].
// A-layout (mfma_f32_16x16x32_bf16): lane l holds A[m=(l&15)][k=ks*32+(l>>4)*8+j].
// ---------------------------------------------------------------------------
__global__ void prep_weights(const float* __restrict__ w1, const float* __restrict__ b1,
                             const float* __restrict__ w2, const float* __restrict__ w3,
                             int4* __restrict__ wf)
{
    const int f = blockIdx.x, l = threadIdx.x;
    const int lq = l >> 4, ln = l & 15;
    union { unsigned short us[8]; int4 v; } u;
    if (f < 8) {
        const int mt = f >> 1, ks = f & 1, m = mt * 16 + ln;
        #pragma unroll
        for (int j = 0; j < 8; ++j) {
            const int k = ks * 32 + lq * 8 + j;
            float v = (k < 48) ? w1[m * 48 + k] : ((k == 48) ? b1[m] : 0.0f);
            u.us[j] = f2bf(v);
        }
    } else if (f < 16) {
        const int ff = f - 8, mt = ff >> 1, ks = ff & 1, m = mt * 16 + ln;
        #pragma unroll
        for (int j = 0; j < 8; ++j)
            u.us[j] = f2bf(w2[m * 64 + (ks * 32 + lq * 8 + j)]);
    } else {
        const int ks = f - 16, m = ln;
        #pragma unroll
        for (int j = 0; j < 8; ++j)
            u.us[j] = f2bf(w3[m * 64 + (ks * 32 + lq * 8 + j)]);
    }
    wf[f * 64 + l] = u.v;
}

// ---------------------------------------------------------------------------
// MLP GEMM body. yb holds y[px][64] bf16; wave wv owns px in [wv*64, wv*64+64).
// A-fragments from prepacked wf (coalesced). Residual via getres, store via
// putout (planar bf16).
// ---------------------------------------------------------------------------
template<typename ResF, typename OutF>
static __device__ __forceinline__ void mlp_gemm(
    char* yb, int lane, int px0,
    const int4* __restrict__ wf, const float* __restrict__ b2,
    const float* __restrict__ umr, ResF getres, OutF putout)
{
    const int lq = lane >> 4, ln = lane & 15;

    float umv[4];
    #pragma unroll
    for (int nt = 0; nt < 4; ++nt)
        umv[nt] = (umr[px0 + nt * 16 + ln] < UPDATE_RATE) ? 1.0f : 0.0f;

    // ---- L1: 64 <- 48(+bias row k=48), relu; h1 in place -------------------
    bf16x8 a1f[8];
    #pragma unroll
    for (int f = 0; f < 8; ++f)
        a1f[f] = __builtin_bit_cast(bf16x8, wf[f * 64 + lane]);

    #pragma unroll
    for (int nt = 0; nt < 4; ++nt) {
        const int px = px0 + nt * 16 + ln;
        bf16x8 bb0 = *(const bf16x8*)(yb + ybyte(px, lq));
        bf16x8 bb1 = *(const bf16x8*)(yb + ybyte(px, 4 + lq));
        #pragma unroll
        for (int mt = 0; mt < 4; ++mt) {
            f32x4 z = {0.f, 0.f, 0.f, 0.f};
            z = MFMA16(a1f[2 * mt],     bb0, z);
            z = MFMA16(a1f[2 * mt + 1], bb1, z);
            union { unsigned w[2]; uint2 v; } pk;
            pk.w[0] = pack2(fmaxf(z[0], 0.f), fmaxf(z[1], 0.f));
            pk.w[1] = pack2(fmaxf(z[2], 0.f), fmaxf(z[3], 0.f));
            *(uint2*)(yb + ybyte(px, 2 * mt + (lq >> 1)) + (lq & 1) * 8) = pk.v;
        }
    }

    // ---- L2: 64 <- 64, +b2, relu; h2 in place -------------------------------
    bf16x8 a2f[8];
    #pragma unroll
    for (int f = 0; f < 8; ++f)
        a2f[f] = __builtin_bit_cast(bf16x8, wf[(8 + f) * 64 + lane]);
    f32x4 b2v[4];
    #pragma unroll
    for (int mt = 0; mt < 4; ++mt)
        b2v[mt] = *(const f32x4*)(b2 + mt * 16 + lq * 4);

    #pragma unroll
    for (int nt = 0; nt < 4; ++nt) {
        const int px = px0 + nt * 16 + ln;
        bf16x8 bb0 = *(const bf16x8*)(yb + ybyte(px, lq));
        bf16x8 bb1 = *(const bf16x8*)(yb + ybyte(px, 4 + lq));
        #pragma unroll
        for (int mt = 0; mt < 4; ++mt) {
            f32x4 z = {0.f, 0.f, 0.f, 0.f};
            z = MFMA16(a2f[2 * mt],     bb0, z);
            z = MFMA16(a2f[2 * mt + 1], bb1, z);
            z = z + b2v[mt];
            union { unsigned w[2]; uint2 v; } pk;
            pk.w[0] = pack2(fmaxf(z[0], 0.f), fmaxf(z[1], 0.f));
            pk.w[1] = pack2(fmaxf(z[2], 0.f), fmaxf(z[3], 0.f));
            *(uint2*)(yb + ybyte(px, 2 * mt + (lq >> 1)) + (lq & 1) * 8) = pk.v;
        }
    }

    // ---- L3: 16 <- 64 + residual epilogue -----------------------------------
    bf16x8 a3f0 = __builtin_bit_cast(bf16x8, wf[16 * 64 + lane]);
    bf16x8 a3f1 = __builtin_bit_cast(bf16x8, wf[17 * 64 + lane]);

    #pragma unroll
    for (int nt = 0; nt < 4; ++nt) {
        const int px = px0 + nt * 16 + ln;
        bf16x8 bb0 = *(const bf16x8*)(yb + ybyte(px, lq));
        bf16x8 bb1 = *(const bf16x8*)(yb + ybyte(px, 4 + lq));
        f32x4 z = {0.f, 0.f, 0.f, 0.f};
        z = MFMA16(a3f0, bb0, z);
        z = MFMA16(a3f1, bb1, z);
        f32x4 res = getres(px, lq, nt);
        #pragma unroll
        for (int r = 0; r < 4; ++r)
            putout(px, lq, r, res[r] + z[r] * umv[nt]);
    }
}

// ---------------------------------------------------------------------------
// First step: f32 planar input -> bf16 planar unmasked state + pre mask.
// LDS exactly 32 KB (sd overlays ybuf; live ranges disjoint across B2).
// ---------------------------------------------------------------------------
__global__ __launch_bounds__(256) void nca_first(
    const float* __restrict__ x,
    const float* __restrict__ um,
    const int4*  __restrict__ wf,
    const float* __restrict__ b2,
    ushort_t* __restrict__ xout,
    unsigned char* __restrict__ preb_out)
{
    __shared__ char smem[256 * 128];          // 32 KB
    char*     yb = smem;
    unsigned* sd = (unsigned*)smem;           // [NC][NW], dead after B2

    const int t = threadIdx.x, bx = blockIdx.x;
    const int h = ((bx & 7) << 5) | (bx >> 3);       // XCD-chunked row swizzle
    const int b = blockIdx.y;
    const int hm = (h - 1) & 255, hp = (h + 1) & 255;
    const size_t cs = (size_t)NH * NW;
    const size_t base = (size_t)b * NC * cs;

    // ---- pre-alive: own 3x3 f32 alpha window (coalesced, cache-hot) --------
    {
        const float* a3p = x + base + 3 * cs;
        float mx = -1e30f;
        #pragma unroll
        for (int r = 0; r < 3; ++r) {
            const float* rp = a3p + (size_t)((h - 1 + r) & 255) * NW;
            #pragma unroll
            for (int d = 0; d < 3; ++d)
                mx = fmaxf(mx, rp[(t - 1 + d) & 255]);
        }
        preb_out[((size_t)b * NH + h) * NW + t] = (mx > ALIVE_THRESH) ? 1 : 0;
    }

    // ---- vertical smooth/diff -> sd -----------------------------------------
    float mreg[NC], dreg[NC];
    #pragma unroll
    for (int c = 0; c < NC; ++c) {
        const float* xc = x + base + (size_t)c * cs;
        float top = xc[(size_t)hm * NW + t];
        float mid = xc[(size_t)h  * NW + t];
        float bot = xc[(size_t)hp * NW + t];
        sd[c * NW + t] = pack2(top + 2.0f * mid + bot, bot - top);
        mreg[c] = mid; dreg[c] = bot - top;
    }
    __syncthreads();                                  // B1: sd ready

    const int tm = (t - 1) & 255, tp = (t + 1) & 255;
    unsigned yp[24];
    {
        unsigned short ys[48];
        #pragma unroll
        for (int c = 0; c < NC; ++c) {
            unsigned L = sd[c * NW + tm], R = sd[c * NW + tp];
            float sl = bfbits(L, 0), dl = bfbits(L, 1);
            float sr = bfbits(R, 0), dr = bfbits(R, 1);
            ys[3 * c + 0] = f2bf(mreg[c]);
            ys[3 * c + 1] = f2bf(sr - sl);
            ys[3 * c + 2] = f2bf(dl + 2.0f * dreg[c] + dr);
        }
        #pragma unroll
        for (int i = 0; i < 24; ++i)
            yp[i] = (unsigned)ys[2 * i] | ((unsigned)ys[2 * i + 1] << 16);
    }
    __syncthreads();                                  // B2: sd dead, ybuf safe

    #pragma unroll
    for (int g = 0; g < 6; ++g) {
        union { unsigned w[4]; int4 v; } pk;
        pk.w[0] = yp[4 * g]; pk.w[1] = yp[4 * g + 1];
        pk.w[2] = yp[4 * g + 2]; pk.w[3] = yp[4 * g + 3];
        *(int4*)(yb + ybyte(t, g)) = pk.v;
    }
    { int4 br; br.x = 0x3F80; br.y = 0; br.z = 0; br.w = 0;
      *(int4*)(yb + ybyte(t, 6)) = br; }              // k=48 -> 1.0 (bias)
    { int4 zz; zz.x = zz.y = zz.z = zz.w = 0;
      *(int4*)(yb + ybyte(t, 7)) = zz; }

    const int lane = t & 63, wv = t >> 6;
    const float* umr = um + ((size_t)b * NH + h) * NW;

    auto getres = [&](int px, int lq, int) -> f32x4 {
        f32x4 r;
        #pragma unroll
        for (int i = 0; i < 4; ++i)
            r[i] = x[base + (size_t)(lq * 4 + i) * cs + (size_t)h * NW + px];
        return r;
    };
    auto putout = [&](int px, int lq, int r, float v) {
        xout[base + (size_t)(lq * 4 + r) * cs + (size_t)h * NW + px] = f2bf(v);
    };
    mlp_gemm(yb, lane, wv * 64, wf, b2, umr, getres, putout);
}

// ---------------------------------------------------------------------------
// Later steps: bf16 planar unmasked state + prev pre mask in; reconstruct
// pre*post masks in REGISTERS (5x5 planar alpha window, all coalesced).
// ---------------------------------------------------------------------------
__global__ __launch_bounds__(256) void nca_step(
    const ushort_t* __restrict__ xin,
    const unsigned char* __restrict__ preb_in,
    const float* __restrict__ um,
    const int4*  __restrict__ wf,
    const float* __restrict__ b2,
    ushort_t* __restrict__ xout,
    unsigned char* __restrict__ preb_out)
{
    __shared__ char smem[256 * 128];          // 32 KB
    char*     yb = smem;
    unsigned* sd = (unsigned*)smem;

    const int t = threadIdx.x, bx = blockIdx.x;
    const int h = ((bx & 7) << 5) | (bx >> 3);
    const int b = blockIdx.y;
    const int hm = (h - 1) & 255, hp = (h + 1) & 255;
    const size_t cs = (size_t)NH * NW;
    const size_t base = (size_t)b * NC * cs;
    const size_t prow = (size_t)b * NH;

    // ---- 5x5 alpha window (planar, coalesced) -------------------------------
    float a[5][5];
    {
        const ushort_t* a3p = xin + base + 3 * cs;
        #pragma unroll
        for (int j = 0; j < 5; ++j) {
            const ushort_t* rp = a3p + (size_t)((h - 2 + j) & 255) * NW;
            #pragma unroll
            for (int d = 0; d < 5; ++d)
                a[j][d] = bf2f(rp[(t - 2 + d) & 255]);
        }
    }

    // ---- post(prev) & combined masks for rows h-1..h+1, cols t-1..t+1 ------
    float m3x3[3][3];
    #pragma unroll
    for (int r = 0; r < 3; ++r) {
        float cm[5];
        #pragma unroll
        for (int d = 0; d < 5; ++d)
            cm[d] = fmaxf(fmaxf(a[r][d], a[r + 1][d]), a[r + 2][d]);
        #pragma unroll
        for (int dd = 0; dd < 3; ++dd) {
            float post = fmaxf(fmaxf(cm[dd], cm[dd + 1]), cm[dd + 2]);
            const int hh = (h - 1 + r) & 255, uu = (t - 1 + dd) & 255;
            unsigned char p = preb_in[(prow + hh) * NW + uu];
            m3x3[r][dd] = (post > ALIVE_THRESH && p) ? 1.0f : 0.0f;
        }
    }

    // ---- pre mask of THIS step ----------------------------------------------
    {
        float pm = 0.0f;
        #pragma unroll
        for (int r = 0; r < 3; ++r)
            #pragma unroll
            for (int dd = 0; dd < 3; ++dd)
                pm = fmaxf(pm, a[1 + r][1 + dd] * m3x3[r][dd]);
        preb_out[(prow + h) * NW + t] = (pm > ALIVE_THRESH) ? 1 : 0;
    }

    const float m0 = m3x3[0][1], m1 = m3x3[1][1], m2 = m3x3[2][1];

    // ---- vertical smooth/diff on masked state -> sd (planar loads) ----------
    float mreg[NC], dreg[NC];
    #pragma unroll
    for (int c = 0; c < NC; ++c) {
        float top, mid, bot;
        if (c == 3) { top = a[1][2] * m0; mid = a[2][2] * m1; bot = a[3][2] * m2; }
        else {
            const ushort_t* xc = xin + base + (size_t)c * cs;
            top = bf2f(xc[(size_t)hm * NW + t]) * m0;
            mid = bf2f(xc[(size_t)h  * NW + t]) * m1;
            bot = bf2f(xc[(size_t)hp * NW + t]) * m2;
        }
        sd[c * NW + t] = pack2(top + 2.0f * mid + bot, bot - top);
        mreg[c] = mid; dreg[c] = bot - top;
    }
    __syncthreads();                                  // B1: sd ready

    const int tm = (t - 1) & 255, tp = (t + 1) & 255;
    unsigned yp[24];
    {
        unsigned short ys[48];
        #pragma unroll
        for (int c = 0; c < NC; ++c) {
            unsigned L = sd[c * NW + tm], R = sd[c * NW + tp];
            float sl = bfbits(L, 0), dl = bfbits(L, 1);
            float sr = bfbits(R, 0), dr = bfbits(R, 1);
            ys[3 * c + 0] = f2bf(mreg[c]);
            ys[3 * c + 1] = f2bf(sr - sl);
            ys[3 * c + 2] = f2bf(dl + 2.0f * dreg[c] + dr);
        }
        #pragma unroll
        for (int i = 0; i < 24; ++i)
            yp[i] = (unsigned)ys[2 * i] | ((unsigned)ys[2 * i + 1] << 16);
    }
    __syncthreads();                                  // B2: sd dead, ybuf safe

    #pragma unroll
    for (int g = 0; g < 6; ++g) {
        union { unsigned w[4]; int4 v; } pk;
        pk.w[0] = yp[4 * g]; pk.w[1] = yp[4 * g + 1];
        pk.w[2] = yp[4 * g + 2]; pk.w[3] = yp[4 * g + 3];
        *(int4*)(yb + ybyte(t, g)) = pk.v;
    }
    { int4 br; br.x = 0x3F80; br.y = 0; br.z = 0; br.w = 0;
      *(int4*)(yb + ybyte(t, 6)) = br; }
    { int4 zz; zz.x = zz.y = zz.z = zz.w = 0;
      *(int4*)(yb + ybyte(t, 7)) = zz; }

    const int lane = t & 63, wv = t >> 6;
    const float* umr = um + (prow + h) * NW;

    // residual mask for px via wave shuffle (wave wv owns px = wv*64 + lane)
    auto getres = [&](int px, int lq, int) -> f32x4 {
        const float mm = __shfl(m1, px & 63);
        f32x4 r;
        #pragma unroll
        for (int i = 0; i < 4; ++i)
            r[i] = bf2f(xin[base + (size_t)(lq * 4 + i) * cs + (size_t)h * NW + px]) * mm;
        return r;
    };
    auto putout = [&](int px, int lq, int r, float v) {
        xout[base + (size_t)(lq * 4 + r) * cs + (size_t)h * NW + px] = f2bf(v);
    };
    mlp_gemm(yb, lane, wv * 64, wf, b2, umr, getres, putout);
}

// ---------------------------------------------------------------------------
// Final: post-alive on bf16 planar state, apply pre*post, f32 planar out.
// Zero LDS, zero barriers.
// ---------------------------------------------------------------------------
__global__ __launch_bounds__(256) void nca_final(
    const ushort_t* __restrict__ xin,
    const unsigned char* __restrict__ preb,
    float* __restrict__ xout)
{
    const int t = threadIdx.x, bx = blockIdx.x;
    const int h = ((bx & 7) << 5) | (bx >> 3);
    const int b = blockIdx.y;
    const size_t cs = (size_t)NH * NW;
    const size_t base = (size_t)b * NC * cs;

    const ushort_t* a3p = xin + base + 3 * cs;
    float mx = -1e30f;
    #pragma unroll
    for (int r = 0; r < 3; ++r) {
        const ushort_t* rp = a3p + (size_t)((h - 1 + r) & 255) * NW;
        #pragma unroll
        for (int d = 0; d < 3; ++d)
            mx = fmaxf(mx, bf2f(rp[(t - 1 + d) & 255]));
    }
    const float m = (mx > ALIVE_THRESH && preb[((size_t)b * NH + h) * NW + t])
                        ? 1.0f : 0.0f;

    const size_t off = (size_t)h * NW + t;
    #pragma unroll
    for (int c = 0; c < NC; ++c)
        xout[base + (size_t)c * cs + off] = bf2f(xin[base + (size_t)c * cs + off]) * m;
}

// ---------------------------------------------------------------------------
extern "C" void kernel_launch(void* const* d_in, const int* in_sizes, int n_in,
                              void* d_out, int out_size, void* d_ws, size_t ws_size,
                              hipStream_t stream) {
    const float* x  = (const float*)d_in[0];
    const float* w1 = (const float*)d_in[1];
    const float* b1 = (const float*)d_in[2];
    const float* w2 = (const float*)d_in[3];
    const float* b2 = (const float*)d_in[4];
    const float* w3 = (const float*)d_in[5];
    const float* um = (const float*)d_in[6];
    const int steps = in_sizes[6] / (NB * NH * NW);

    const size_t npix  = (size_t)NB * NH * NW;
    const size_t nelem = (size_t)NB * NC * NH * NW;

    ushort_t* bfA        = (ushort_t*)d_ws;                 // 16 MB
    ushort_t* bfB        = bfA + nelem;                     // 16 MB
    unsigned char* prebA = (unsigned char*)(bfB + nelem);   // 512 KB
    unsigned char* prebB = prebA + npix;                    // 512 KB
    int4* wf             = (int4*)(prebB + npix);           // 18 KB
    float* xout          = (float*)d_out;

    prep_weights<<<18, 64, 0, stream>>>(w1, b1, w2, w3, wf);

    dim3 grd(NH, NB);

    const ushort_t* cur = bfA;
    unsigned char* preb_last = prebA;

    for (int i = 0; i < steps; ++i) {
        const float* um_i = um + (size_t)i * npix;
        ushort_t* bfo      = (i % 2 == 0) ? bfA : bfB;
        unsigned char* po  = (i % 2 == 0) ? prebA : prebB;
        unsigned char* pin = (i % 2 == 0) ? prebB : prebA;

        if (i == 0)
            nca_first<<<grd, 256, 0, stream>>>(x, um_i, wf, b2, bfo, po);
        else
            nca_step<<<grd, 256, 0, stream>>>(cur, pin, um_i, wf, b2, bfo, po);
        cur = bfo;
        preb_last = po;
    }

    nca_final<<<grd, 256, 0, stream>>>(cur, preb_last, xout);
}